// Round 2
// baseline (677.172 us; speedup 1.0000x reference)
//
#include <hip/hip_runtime.h>
#include <math.h>

#define BATCH 4096
#define NPTS  2000
#define DIM   9
#define NPACK 45   // upper triangle of 9x9

// ---------------------------------------------------------------------------
// Kernel 1: B_k = G^T diag(w) G  per batch, w = 1/(|alpha|+1e-8) (fp32, like ref)
// Accumulate the 45 unique entries in fp64. One block per batch element.
// ---------------------------------------------------------------------------
__global__ __launch_bounds__(256) void bk_accum(const float* __restrict__ G,
                                                const float* __restrict__ alpha,
                                                double* __restrict__ Bk) {
  const int b = blockIdx.x;
  const float* Gb = G + (size_t)b * NPTS * DIM;
  const float* ab = alpha + (size_t)b * NPTS;

  double acc[NPACK];
#pragma unroll
  for (int k = 0; k < NPACK; ++k) acc[k] = 0.0;

  // 4 rows per thread-iteration: 36 floats = 9 float4 (144B, 16-aligned)
  for (int grp = threadIdx.x; grp < NPTS / 4; grp += 256) {
    const float4 a4 = *reinterpret_cast<const float4*>(ab + grp * 4);
    const float4* gp = reinterpret_cast<const float4*>(Gb + (size_t)grp * 36);
    float g36[36];
#pragma unroll
    for (int i = 0; i < 9; ++i) {
      float4 t = gp[i];
      g36[i*4+0] = t.x; g36[i*4+1] = t.y; g36[i*4+2] = t.z; g36[i*4+3] = t.w;
    }
    const float aw[4] = {a4.x, a4.y, a4.z, a4.w};
#pragma unroll
    for (int r = 0; r < 4; ++r) {
      const float w = 1.0f / (fabsf(aw[r]) + 1e-8f);  // match reference fp32 weights
      const double dw = (double)w;
      double dg[9];
#pragma unroll
      for (int i = 0; i < 9; ++i) dg[i] = (double)g36[r*9 + i];
      int k = 0;
#pragma unroll
      for (int i = 0; i < 9; ++i) {
        const double wgi = dw * dg[i];
#pragma unroll
        for (int j = i; j < 9; ++j) {
          acc[k] = fma(wgi, dg[j], acc[k]);
          ++k;
        }
      }
    }
  }

  // intra-wave butterfly reduce (64-bit shuffles)
#pragma unroll
  for (int k = 0; k < NPACK; ++k) {
    double v = acc[k];
#pragma unroll
    for (int off = 32; off > 0; off >>= 1) v += __shfl_down(v, off, 64);
    acc[k] = v;
  }

  __shared__ double red[4][NPACK];
  const int wave = threadIdx.x >> 6;
  const int lane = threadIdx.x & 63;
  if (lane == 0) {
#pragma unroll
    for (int k = 0; k < NPACK; ++k) red[wave][k] = acc[k];
  }
  __syncthreads();
  if (threadIdx.x < NPACK) {
    const double s = red[0][threadIdx.x] + red[1][threadIdx.x] +
                     red[2][threadIdx.x] + red[3][threadIdx.x];
    Bk[(size_t)b * NPACK + threadIdx.x] = s;
  }
}

// ---------------------------------------------------------------------------
// Kernel 2: min-eigenvector of each 9x9 symmetric matrix via cyclic Jacobi
// (fp64). One thread per matrix. Sign ambiguity is fine (caller takes |.|).
// ---------------------------------------------------------------------------
__global__ __launch_bounds__(64) void eig_min(const double* __restrict__ Bk,
                                              double* __restrict__ U) {
  const int b = blockIdx.x * 64 + threadIdx.x;
  if (b >= BATCH) return;

  double A[9][9], V[9][9];
  {
    const double* src = Bk + (size_t)b * NPACK;
    int k = 0;
    for (int i = 0; i < 9; ++i)
      for (int j = i; j < 9; ++j) {
        const double v = src[k++];
        A[i][j] = v; A[j][i] = v;
      }
  }
  for (int i = 0; i < 9; ++i)
    for (int j = 0; j < 9; ++j) V[i][j] = (i == j) ? 1.0 : 0.0;

  for (int sweep = 0; sweep < 20; ++sweep) {
    double off = 0.0, dia = 0.0;
    for (int p = 0; p < 9; ++p) {
      dia += A[p][p] * A[p][p];
      for (int q = p + 1; q < 9; ++q) off += A[p][q] * A[p][q];
    }
    if (off <= 1e-30 * dia) break;  // quadratic convergence: ~8 sweeps typical

    for (int p = 0; p < 8; ++p) {
      for (int q = p + 1; q < 9; ++q) {
        const double apq = A[p][q];
        if (fabs(apq) < 1e-300) continue;  // avoids 0/0 -> NaN in tau
        const double app = A[p][p], aqq = A[q][q];
        const double tau = (aqq - app) / (2.0 * apq);
        // stable root of t^2 + 2*tau*t - 1 = 0; tau=inf overflow -> t=0 (no-op)
        const double t = ((tau >= 0.0) ? 1.0 : -1.0) /
                         (fabs(tau) + sqrt(1.0 + tau * tau));
        const double c = 1.0 / sqrt(1.0 + t * t);
        const double s = t * c;
        // A <- A J  (columns p,q)
        for (int k = 0; k < 9; ++k) {
          const double akp = A[k][p], akq = A[k][q];
          A[k][p] = c * akp - s * akq;
          A[k][q] = s * akp + c * akq;
        }
        // A <- J^T A  (rows p,q)
        for (int k = 0; k < 9; ++k) {
          const double apk = A[p][k], aqk = A[q][k];
          A[p][k] = c * apk - s * aqk;
          A[q][k] = s * apk + c * aqk;
        }
        // V <- V J
        for (int k = 0; k < 9; ++k) {
          const double vkp = V[k][p], vkq = V[k][q];
          V[k][p] = c * vkp - s * vkq;
          V[k][q] = s * vkp + c * vkq;
        }
      }
    }
  }

  int mi = 0;
  double mv = A[0][0];
  for (int i = 1; i < 9; ++i)
    if (A[i][i] < mv) { mv = A[i][i]; mi = i; }
  for (int i = 0; i < 9; ++i) U[(size_t)b * 9 + i] = V[i][mi];
}

// ---------------------------------------------------------------------------
// Kernel 3: out[b][n] = |G[b][n] . u[b]|
// ---------------------------------------------------------------------------
__global__ __launch_bounds__(256) void solve_out(const float* __restrict__ G,
                                                 const double* __restrict__ U,
                                                 float* __restrict__ out) {
  const int b = blockIdx.y;
  const int grp = blockIdx.x * 256 + threadIdx.x;
  if (grp >= NPTS / 4) return;

  double u[9];
#pragma unroll
  for (int i = 0; i < 9; ++i) u[i] = U[(size_t)b * 9 + i];

  const float4* gp =
      reinterpret_cast<const float4*>(G + (size_t)b * NPTS * DIM + (size_t)grp * 36);
  float g36[36];
#pragma unroll
  for (int i = 0; i < 9; ++i) {
    float4 t = gp[i];
    g36[i*4+0] = t.x; g36[i*4+1] = t.y; g36[i*4+2] = t.z; g36[i*4+3] = t.w;
  }

  float* o = out + (size_t)b * NPTS + (size_t)grp * 4;
#pragma unroll
  for (int r = 0; r < 4; ++r) {
    double acc = 0.0;
#pragma unroll
    for (int i = 0; i < 9; ++i) acc = fma((double)g36[r*9 + i], u[i], acc);
    o[r] = (float)fabs(acc);
  }
}

// ---------------------------------------------------------------------------
extern "C" void kernel_launch(void* const* d_in, const int* in_sizes, int n_in,
                              void* d_out, int out_size, void* d_ws, size_t ws_size,
                              hipStream_t stream) {
  const float* G     = (const float*)d_in[0];
  const float* alpha = (const float*)d_in[1];
  float* out = (float*)d_out;

  double* Bk = (double*)d_ws;                                            // 4096*45 fp64 = 1.47 MB
  double* U  = (double*)((char*)d_ws + (size_t)BATCH * NPACK * sizeof(double)); // +0.29 MB

  bk_accum<<<BATCH, 256, 0, stream>>>(G, alpha, Bk);
  eig_min<<<BATCH / 64, 64, 0, stream>>>(Bk, U);
  dim3 gridC((NPTS / 4 + 255) / 256, BATCH);
  solve_out<<<gridC, 256, 0, stream>>>(G, U, out);
}